// Round 15
// baseline (290.510 us; speedup 1.0000x reference)
//
#include <hip/hip_runtime.h>
#include <hip/hip_bf16.h>

// Problem constants (from reference)
#define BATCH   16
#define TT      512
#define CC      768
#define D_IN    3072
#define HIDDEN  1024
#define LL      255          // (T - 4)/2 + 1
#define OUTROWS 257
#define KSTACK  12288        // D_IN * 4
#define N_DATES 16

typedef float f32x4  __attribute__((ext_vector_type(4)));
typedef float f32x16 __attribute__((ext_vector_type(16)));
typedef __bf16 bf16x8 __attribute__((ext_vector_type(8)));
typedef unsigned short u16;

// round-to-nearest-even f32 -> bf16 bits
__device__ __forceinline__ u16 f2bf(float f) {
    unsigned u = __builtin_bit_cast(unsigned, f);
    u = (u + 0x7FFFu + ((u >> 16) & 1u)) >> 16;
    return (u16)u;
}

__device__ __forceinline__ bf16x8 lds_read8(const u16* p) {
    return __builtin_bit_cast(bf16x8, *(const uint4*)p);
}

// async global->LDS, 16B per lane. LDS dest is wave-uniform base (+lane*16 by HW),
// global src is per-lane.
__device__ __forceinline__ void gload16(const u16* g, u16* l) {
    __builtin_amdgcn_global_load_lds(
        (const __attribute__((address_space(1))) void*)g,
        (__attribute__((address_space(3))) void*)l, 16, 0, 0);
}

// ---------------- fused f32->bf16 conversion: W_stack | spikes | W_embed(used dates) ----------------
__global__ __launch_bounds__(256) void cvt_all(const float* __restrict__ Ws,
                                               const float* __restrict__ spk,
                                               const float* __restrict__ We,
                                               const int* __restrict__ date_idx,
                                               u16* __restrict__ oWs, u16* __restrict__ oSpk,
                                               u16* __restrict__ oWe, int do_bf) {
    __shared__ int dates[BATCH];
    if (threadIdx.x < BATCH) dates[threadIdx.x] = date_idx[threadIdx.x];
    __syncthreads();
    const size_t NW = (size_t)HIDDEN * KSTACK / 4;
    const size_t NS = (size_t)BATCH * TT * CC / 4;
    const size_t NE = (size_t)N_DATES * D_IN * CC / 4;
    const unsigned DSZ = (unsigned)(D_IN * CC / 4);
    const size_t total = do_bf ? (NW + NS + NE) : NW;
    for (size_t i = (size_t)blockIdx.x * 256 + threadIdx.x; i < total; i += (size_t)gridDim.x * 256) {
        const float* src; u16* dst; size_t off;
        if (i < NW)            { src = Ws;  dst = oWs;  off = i; }
        else if (i < NW + NS)  { src = spk; dst = oSpk; off = i - NW; }
        else {
            off = i - NW - NS;
            const int date = (int)((unsigned)off / DSZ);
            bool used = false;
            #pragma unroll
            for (int b = 0; b < BATCH; ++b) used |= (dates[b] == date);
            if (!used) continue;
            src = We; dst = oWe;
        }
        float4 v = *(const float4*)(src + off * 4);
        ushort4 o = make_ushort4(f2bf(v.x), f2bf(v.y), f2bf(v.z), f2bf(v.w));
        *(ushort4*)(dst + off * 4) = o;
    }
}

// ---------------- GEMM1 (bf16): 256Mx192N tile, 4 waves, 2-slot dbuf, 2 blocks/CU ----------------
// (verified round 11 — unchanged)
__global__ __launch_bounds__(256, 2) void gemm1_bf(const u16* __restrict__ spk,
                                                   const u16* __restrict__ wemb,
                                                   const float* __restrict__ b_embed,
                                                   const int* __restrict__ date_idx,
                                                   u16* __restrict__ x1) {
    const int nwg = 512;
    const int cpx = nwg / 8;                  // 64
    const int f   = blockIdx.x;
    const int swz = (f & 7) * cpx + (f >> 3); // bijective (nwg % 8 == 0)
    const int bb  = swz >> 5;
    const int rem = swz & 31;
    const int m0  = (rem >> 4) * 256;
    const int n0  = (rem & 15) * 192;

    const int date = date_idx[bb];
    const u16* A  = spk  + (size_t)bb   * TT * CC;
    const u16* Bw = wemb + (size_t)date * D_IN * CC;
    const int S = CC / 32;                    // 24

    __shared__ u16 Asm[2][128 * 64];
    __shared__ u16 Bsm[2][96 * 64];

    const int tid  = threadIdx.x;
    const int lane = tid & 63;
    const int wave = tid >> 6;
    const int wm = wave >> 1;
    const int wn = wave & 1;

    const int lrow  = lane >> 3;
    const int scol  = ((lane & 7) ^ lrow) << 3;
    const int chalf = scol >> 5;
    const int gk    = scol & 31;

    f32x4 acc[8][6] = {};

    auto STAGE = [&](int slice, int slot) {
        const int k0 = slice * 32;
        u16* Ad = Asm[slot];
        u16* Bd = Bsm[slot];
        #pragma unroll
        for (int i = 0; i < 4; ++i) {
            const int rbase = wave * 32 + i * 8;
            const int tr = 2 * (rbase + lrow) + chalf;
            gload16(A + (size_t)(m0 + tr) * CC + k0 + gk, Ad + rbase * 64);
        }
        #pragma unroll
        for (int i = 0; i < 3; ++i) {
            const int rbase = wave * 24 + i * 8;
            const int tr = 2 * (rbase + lrow) + chalf;
            gload16(Bw + (size_t)(n0 + tr) * CC + k0 + gk, Bd + rbase * 64);
        }
    };

    const int krow  = lane & 15;
    const int kcol  = (lane >> 4) << 3;
    const int cfrag = (kcol + ((krow & 1) << 5)) ^ ((krow >> 1) << 3);
    const int urow  = krow >> 1;

    STAGE(0, 0); STAGE(1, 1);
    for (int t = 0; t < S; ++t) {
        if (t + 1 < S) { asm volatile("s_waitcnt vmcnt(7)" ::: "memory"); }
        else           { asm volatile("s_waitcnt vmcnt(0)" ::: "memory"); }
        __builtin_amdgcn_s_barrier();
        const u16* Ab = Asm[t & 1];
        const u16* Bb = Bsm[t & 1];
        bf16x8 bfr[6];
        #pragma unroll
        for (int j = 0; j < 6; ++j)
            bfr[j] = lds_read8(&Bb[(wn * 48 + j * 8 + urow) * 64 + cfrag]);
        __builtin_amdgcn_s_setprio(1);
        #pragma unroll
        for (int i = 0; i < 8; ++i) {
            bf16x8 af = lds_read8(&Ab[(wm * 64 + i * 8 + urow) * 64 + cfrag]);
            #pragma unroll
            for (int j = 0; j < 6; ++j)
                acc[i][j] = __builtin_amdgcn_mfma_f32_16x16x32_bf16(af, bfr[j], acc[i][j], 0, 0, 0);
        }
        __builtin_amdgcn_s_setprio(0);
        __builtin_amdgcn_s_barrier();
        if (t + 2 < S) STAGE(t + 2, t & 1);
    }

    const float* be = b_embed + (size_t)date * D_IN;
    #pragma unroll
    for (int i = 0; i < 8; ++i) {
        #pragma unroll
        for (int j = 0; j < 6; ++j) {
            const int col  = n0 + wn * 96 + j * 16 + (lane & 15);
            const float bias = be[col];
            const int rbase = m0 + wm * 128 + i * 16 + ((lane >> 4) << 2);
            #pragma unroll
            for (int q = 0; q < 4; ++q) {
                float v = acc[i][j][q] + bias;
                float g = 0.5f * v * (1.0f + erff(v * 0.70710678118654752f)) * 32.0f;
                x1[(size_t)bb * TT * D_IN + (size_t)(rbase + q) * D_IN + col] = f2bf(g);
            }
        }
    }
}

// ---------------- GEMM1 (f32 fallback) ----------------
__global__ __launch_bounds__(256) void gemm1_f32(const float* __restrict__ spikes,
                                                 const float* __restrict__ W_embed,
                                                 const float* __restrict__ b_embed,
                                                 const int* __restrict__ date_idx,
                                                 u16* __restrict__ x1) {
    const int m0 = blockIdx.x * 128;
    const int n0 = blockIdx.y * 128;
    const int bb = blockIdx.z;
    const int date = date_idx[bb];
    const float* A  = spikes  + (size_t)bb  * TT * CC;
    const float* Bw = W_embed + (size_t)date * D_IN * CC;

    __shared__ u16 As[128 * 64];
    __shared__ u16 Bs[128 * 64];

    const int tid  = threadIdx.x;
    const int lane = tid & 63;
    const int wave = tid >> 6;
    const int wm = wave >> 1, wn = wave & 1;

    f32x4 acc[4][4] = {};

    for (int k0 = 0; k0 < CC; k0 += 64) {
        {
            const int c4 = tid & 15;
            int r = tid >> 4;
            #pragma unroll
            for (int p = 0; p < 8; ++p, r += 16) {
                float4 va = *(const float4*)(A  + (size_t)(m0 + r) * CC + k0 + c4 * 4);
                float4 vb = *(const float4*)(Bw + (size_t)(n0 + r) * CC + k0 + c4 * 4);
                const int col = c4 * 4;
                const int idx = r * 64 + (col ^ ((r & 7) << 3));
                *(ushort4*)(&As[idx]) = make_ushort4(f2bf(va.x), f2bf(va.y), f2bf(va.z), f2bf(va.w));
                *(ushort4*)(&Bs[idx]) = make_ushort4(f2bf(vb.x), f2bf(vb.y), f2bf(vb.z), f2bf(vb.w));
            }
        }
        __syncthreads();
        #pragma unroll
        for (int kk = 0; kk < 64; kk += 32) {
            bf16x8 af[4], bfr[4];
            const int krow = lane & 15;
            const int kcol = kk + ((lane >> 4) << 3);
            #pragma unroll
            for (int i = 0; i < 4; ++i) {
                const int ra = wm * 64 + i * 16 + krow;
                af[i]  = lds_read8(&As[ra * 64 + (kcol ^ ((ra & 7) << 3))]);
                const int rb = wn * 64 + i * 16 + krow;
                bfr[i] = lds_read8(&Bs[rb * 64 + (kcol ^ ((rb & 7) << 3))]);
            }
            #pragma unroll
            for (int i = 0; i < 4; ++i)
                #pragma unroll
                for (int j = 0; j < 4; ++j)
                    acc[i][j] = __builtin_amdgcn_mfma_f32_16x16x32_bf16(af[i], bfr[j], acc[i][j], 0, 0, 0);
        }
        __syncthreads();
    }

    const float* be = b_embed + (size_t)date * D_IN;
    #pragma unroll
    for (int i = 0; i < 4; ++i) {
        #pragma unroll
        for (int j = 0; j < 4; ++j) {
            const int col  = n0 + wn * 64 + j * 16 + (lane & 15);
            const float bias = be[col];
            const int rbase = m0 + wm * 64 + i * 16 + ((lane >> 4) << 2);
            #pragma unroll
            for (int q = 0; q < 4; ++q) {
                float v = acc[i][j][q] + bias;
                float g = 0.5f * v * (1.0f + erff(v * 0.70710678118654752f)) * 32.0f;
                x1[(size_t)bb * TT * D_IN + (size_t)(rbase + q) * D_IN + col] = f2bf(g);
            }
        }
    }
}

// ---------------- GEMM2: 256Mx128N tile, 4 waves, 3-slot ring, 32x32x16 MFMA ----------------
// Block-sequential LDS layout (zero-conflict): unit = 16B = (tile-row r, k-block kb of 8).
//   off_u16(r, kb) = (r>>5)*1024 + (kb>>1)*512 + (kb&1)*256 + (r&31)*8
// Wave fragment read (group g, k-pair kr) = contiguous 1KiB block at g*1024+kr*512,
// lane l at +lane*8 u16 — perfectly sequential. Unit delivered to lane l holds
// k = kr*16 + (l>>5)*8 + j, exactly the 32x32x16 operand map (row/col = l&31).
// Staging: issue (g,kbp) writes that 1KiB block linearly; per-lane SOURCE =
// row 32g+(l&31), k-block kbp*2+(l>>5). 6 issues/wave/slice -> vmcnt(6) unchanged.
// C/D (HW-verified m74/m101): col=lane&31, row=(reg&3)+8*(reg>>2)+4*(lane>>5).
template <bool WRITE_PART>
__global__ __launch_bounds__(256, 2) void gemm2(const u16* __restrict__ x1,
                                                const u16* __restrict__ Wbf,
                                                float* __restrict__ part,
                                                const float* __restrict__ b_stack,
                                                const float* __restrict__ pos_table,
                                                const int* __restrict__ tstamp,
                                                float* __restrict__ out,
                                                int KS) {
    const int nwg = 8 * KS * BATCH;
    const int cpx = nwg / 8;
    const int f   = blockIdx.x;
    const int swz = (f & 7) * cpx + (f >> 3);   // bijective (nwg % 8 == 0)
    const int bb  = swz / (8 * KS);
    const int rem = swz % (8 * KS);
    const int ks  = rem / 8;
    const int n0  = (rem % 8) * 128;

    const int KCH  = KSTACK / KS;
    const int kbeg = ks * KCH;
    const int S    = KCH / 32;
    const u16* Xb = x1 + (size_t)bb * TT * D_IN;

    __shared__ u16 Asm[3][8 * 1024];   // 16 KiB / slot (256 rows x 32 k)
    __shared__ u16 Bsm[3][4 * 1024];   // 8 KiB / slot (128 rows x 32 k)

    const int tid  = threadIdx.x;
    const int lane = tid & 63;
    const int wave = tid >> 6;
    const int wm = wave >> 1;
    const int wn = wave & 1;

    const int a31   = lane & 31;       // row within 32-group
    const int kb_hi = lane >> 5;       // k-block half select (0/1)

    f32x16 acc[4][2] = {};

    auto STAGE = [&](int slice, int slot) {
        const int k0 = kbeg + slice * 32;
        const int s  = k0 / D_IN;            // window slot (32 | 3072, never straddles)
        const int d0 = k0 % D_IN;
        u16* Ad = Asm[slot];
        u16* Bd = Bsm[slot];
        #pragma unroll
        for (int i = 0; i < 2; ++i) {        // A groups 2w, 2w+1 (8 groups over 4 waves)
            const int g  = wave * 2 + i;
            const int tr = g * 32 + a31;     // tile row 0..255
            #pragma unroll
            for (int kbp = 0; kbp < 2; ++kbp) {
                const int kb = kbp * 2 + kb_hi;
                gload16(Xb + (size_t)(2 * tr + s) * D_IN + d0 + kb * 8,
                        Ad + g * 1024 + kbp * 512);
            }
        }
        {                                    // B group = wave (4 groups)
            const int g  = wave;
            const int tr = g * 32 + a31;     // tile N-row 0..127
            #pragma unroll
            for (int kbp = 0; kbp < 2; ++kbp) {
                const int kb = kbp * 2 + kb_hi;
                gload16(Wbf + (size_t)(n0 + tr) * KSTACK + k0 + kb * 8,
                        Bd + g * 1024 + kbp * 512);
            }
        }
    };

    STAGE(0, 0); STAGE(1, 1);
    int cur = 0;
    for (int t = 0; t < S; ++t) {
        if (t + 1 < S) { asm volatile("s_waitcnt vmcnt(6)" ::: "memory"); }
        else           { asm volatile("s_waitcnt vmcnt(0)" ::: "memory"); }
        __builtin_amdgcn_s_barrier();
        const u16* Ab = Asm[cur];
        const u16* Bb = Bsm[cur];
        bf16x8 af[4][2], bfr[2][2];
        #pragma unroll
        for (int rg = 0; rg < 4; ++rg) {
            const int g = wm * 4 + rg;
            af[rg][0] = lds_read8(&Ab[g * 1024 +       lane * 8]);
            af[rg][1] = lds_read8(&Ab[g * 1024 + 512 + lane * 8]);
        }
        #pragma unroll
        for (int cg = 0; cg < 2; ++cg) {
            const int g = wn * 2 + cg;
            bfr[cg][0] = lds_read8(&Bb[g * 1024 +       lane * 8]);
            bfr[cg][1] = lds_read8(&Bb[g * 1024 + 512 + lane * 8]);
        }
        if (t + 2 < S) {
            const int slot2 = (cur + 2 >= 3) ? cur - 1 : cur + 2;
            STAGE(t + 2, slot2);
        }
        __builtin_amdgcn_s_setprio(1);
        #pragma unroll
        for (int rg = 0; rg < 4; ++rg)
            #pragma unroll
            for (int cg = 0; cg < 2; ++cg) {
                acc[rg][cg] = __builtin_amdgcn_mfma_f32_32x32x16_bf16(af[rg][0], bfr[cg][0], acc[rg][cg], 0, 0, 0);
                acc[rg][cg] = __builtin_amdgcn_mfma_f32_32x32x16_bf16(af[rg][1], bfr[cg][1], acc[rg][cg], 0, 0, 0);
            }
        __builtin_amdgcn_s_setprio(0);
        cur = (cur + 1 >= 3) ? 0 : cur + 1;
    }

    if (WRITE_PART) {
        float* pt = part + ((size_t)(ks * BATCH + bb) * 256) * HIDDEN;
        #pragma unroll
        for (int rg = 0; rg < 4; ++rg)
            #pragma unroll
            for (int cg = 0; cg < 2; ++cg) {
                const int col   = n0 + wn * 64 + cg * 32 + a31;
                const int rbase = wm * 128 + rg * 32 + 4 * kb_hi;
                #pragma unroll
                for (int reg = 0; reg < 16; ++reg) {
                    const int row = rbase + (reg & 3) + 8 * (reg >> 2);
                    pt[(size_t)row * HIDDEN + col] = acc[rg][cg][reg];
                }
            }
    } else {
        #pragma unroll
        for (int rg = 0; rg < 4; ++rg)
            #pragma unroll
            for (int cg = 0; cg < 2; ++cg) {
                const int col   = n0 + wn * 64 + cg * 32 + a31;
                const int rbase = wm * 128 + rg * 32 + 4 * kb_hi;
                #pragma unroll
                for (int reg = 0; reg < 16; ++reg) {
                    const int l = rbase + (reg & 3) + 8 * (reg >> 2);
                    if (l < LL) {
                        const int tsv = tstamp[bb * TT + l];
                        float v = acc[rg][cg][reg] + b_stack[col] + pos_table[(size_t)tsv * HIDDEN + col];
                        out[(size_t)bb * OUTROWS * HIDDEN + (size_t)(2 + l) * HIDDEN + col] = v;
                    }
                }
            }
    }
}

// ---------------- reduce partials + bias + pos_table -> out rows 2.. ----------------
__global__ __launch_bounds__(256) void reduce_ep(const float* __restrict__ part,
                                                 const float* __restrict__ b_stack,
                                                 const float* __restrict__ pos_table,
                                                 const int* __restrict__ tstamp,
                                                 float* __restrict__ out,
                                                 int KS) {
    const int idx = blockIdx.x * 256 + threadIdx.x;
    const int c4  = idx & (HIDDEN / 4 - 1);
    const int r   = idx >> 8;
    if (r >= BATCH * LL) return;
    const int l  = r % LL;
    const int bb = r / LL;
    float4 v = make_float4(0.f, 0.f, 0.f, 0.f);
    for (int ks = 0; ks < KS; ++ks) {
        float4 p = *(const float4*)(part + ((size_t)(ks * BATCH + bb) * 256 + l) * HIDDEN + c4 * 4);
        v.x += p.x; v.y += p.y; v.z += p.z; v.w += p.w;
    }
    const int tsv = tstamp[bb * TT + l];
    float4 bs = *(const float4*)(b_stack + c4 * 4);
    float4 ps = *(const float4*)(pos_table + (size_t)tsv * HIDDEN + c4 * 4);
    v.x += bs.x + ps.x; v.y += bs.y + ps.y; v.z += bs.z + ps.z; v.w += bs.w + ps.w;
    *(float4*)(out + ((size_t)bb * OUTROWS + 2 + l) * HIDDEN + c4 * 4) = v;
}

// ---------------- rows 0/1 + mask + ts outputs ----------------
__global__ __launch_bounds__(256) void epilogue_misc(const int* __restrict__ smask,
                                                     const int* __restrict__ tstamp,
                                                     const int* __restrict__ mask_idx_p,
                                                     const int* __restrict__ session_idx_p,
                                                     const float* __restrict__ prompt_table,
                                                     const float* __restrict__ session_table,
                                                     float* __restrict__ out) {
    const int bb = blockIdx.x;
    const int tid = threadIdx.x;
    const int mi = mask_idx_p[0];
    const int si = session_idx_p[0];
    float* xb = out + (size_t)bb * OUTROWS * HIDDEN;
    for (int i = tid; i < HIDDEN; i += 256) {
        xb[i]          = session_table[(size_t)si * HIDDEN + i];
        xb[HIDDEN + i] = prompt_table[(size_t)mi * HIDDEN + i];
    }
    float* maskout = out + (size_t)BATCH * OUTROWS * HIDDEN + (size_t)bb * OUTROWS;
    float* tsout   = out + (size_t)BATCH * OUTROWS * HIDDEN + (size_t)BATCH * OUTROWS + (size_t)bb * OUTROWS;
    for (int j = tid; j < OUTROWS; j += 256) {
        if (j == 0)      { maskout[0] = 1.0f; tsout[0] = 0.0f; }
        else if (j == 1) { maskout[1] = 1.0f; tsout[1] = 1.0f; }
        else {
            const int l = j - 2;
            int m = 1;
            #pragma unroll
            for (int s = 0; s < 4; ++s) m *= smask[bb * TT + 2 * l + s];
            maskout[j] = (float)m;
            tsout[j]   = (float)(tstamp[bb * TT + l] + 2);
        }
    }
}

extern "C" void kernel_launch(void* const* d_in, const int* in_sizes, int n_in,
                              void* d_out, int out_size, void* d_ws, size_t ws_size,
                              hipStream_t stream) {
    const float* spikes      = (const float*)d_in[0];
    const int*   spikes_mask = (const int*)d_in[1];
    const int*   tstamp      = (const int*)d_in[2];
    const int*   date_idx    = (const int*)d_in[3];
    const int*   mask_idx    = (const int*)d_in[4];
    const int*   session_idx = (const int*)d_in[5];
    const float* W_embed     = (const float*)d_in[6];
    const float* b_embed     = (const float*)d_in[7];
    const float* W_stack     = (const float*)d_in[8];
    const float* b_stack     = (const float*)d_in[9];
    const float* pos_table   = (const float*)d_in[10];
    const float* prompt_tab  = (const float*)d_in[11];
    const float* session_tab = (const float*)d_in[12];
    float* out = (float*)d_out;

    const size_t X1_B   = (size_t)BATCH * TT * D_IN * 2;
    const size_t WBF_B  = (size_t)HIDDEN * KSTACK * 2;
    const size_t PART_B = (size_t)BATCH * 256 * HIDDEN * 4;
    const size_t SPK_B  = (size_t)BATCH * TT * CC * 2;
    const size_t WEMB_B = (size_t)N_DATES * D_IN * CC * 2;
    const size_t BASE   = X1_B + WBF_B;
    const size_t UNION_BF = SPK_B + WEMB_B;

    u16*   x1    = (u16*)d_ws;
    u16*   Wbf   = (u16*)((char*)d_ws + X1_B);
    u16*   spkbf = (u16*)((char*)d_ws + BASE);
    u16*   wembf = (u16*)((char*)d_ws + BASE + SPK_B);
    float* part  = (float*)((char*)d_ws + BASE);

    const bool use_bf = (ws_size >= BASE + UNION_BF);
    int KS = 0;
    if (use_bf) KS = 4;
    else {
        size_t rem = (ws_size > BASE) ? (ws_size - BASE) : 0;
        KS = (int)(rem / PART_B); if (KS > 4) KS = 4;
    }

    cvt_all<<<2048, 256, 0, stream>>>(W_stack, spikes, W_embed, date_idx,
                                      Wbf, spkbf, wembf, use_bf ? 1 : 0);

    if (use_bf) {
        gemm1_bf<<<512, 256, 0, stream>>>(spkbf, wembf, b_embed, date_idx, x1);
    } else {
        gemm1_f32<<<dim3(TT / 128, D_IN / 128, BATCH), 256, 0, stream>>>(spikes, W_embed, b_embed, date_idx, x1);
    }

    if (KS > 0) {
        gemm2<true><<<8 * KS * BATCH, 256, 0, stream>>>(x1, Wbf, part, b_stack, pos_table, tstamp, out, KS);
        reduce_ep<<<(BATCH * LL * (HIDDEN / 4) + 255) / 256, 256, 0, stream>>>(part, b_stack, pos_table, tstamp, out, KS);
    } else {
        gemm2<false><<<8 * 1 * BATCH, 256, 0, stream>>>(x1, Wbf, part, b_stack, pos_table, tstamp, out, 1);
    }
    epilogue_misc<<<BATCH, 256, 0, stream>>>(spikes_mask, tstamp, mask_idx, session_idx,
                                             prompt_tab, session_tab, out);
}

// Round 16
// 239.672 us; speedup vs baseline: 1.2121x; 1.2121x over previous
//
#include <hip/hip_runtime.h>
#include <hip/hip_bf16.h>

// Problem constants (from reference)
#define BATCH   16
#define TT      512
#define CC      768
#define D_IN    3072
#define HIDDEN  1024
#define LL      255          // (T - 4)/2 + 1
#define OUTROWS 257
#define KSTACK  12288        // D_IN * 4
#define N_DATES 16

typedef float f32x4  __attribute__((ext_vector_type(4)));
typedef __bf16 bf16x8 __attribute__((ext_vector_type(8)));
typedef unsigned short u16;

// round-to-nearest-even f32 -> bf16 bits
__device__ __forceinline__ u16 f2bf(float f) {
    unsigned u = __builtin_bit_cast(unsigned, f);
    u = (u + 0x7FFFu + ((u >> 16) & 1u)) >> 16;
    return (u16)u;
}

__device__ __forceinline__ bf16x8 lds_read8(const u16* p) {
    return __builtin_bit_cast(bf16x8, *(const uint4*)p);
}

// async global->LDS, 16B per lane. LDS dest is wave-uniform base (+lane*16 by HW),
// global src is per-lane.
__device__ __forceinline__ void gload16(const u16* g, u16* l) {
    __builtin_amdgcn_global_load_lds(
        (const __attribute__((address_space(1))) void*)g,
        (__attribute__((address_space(3))) void*)l, 16, 0, 0);
}

// ---------------- fused f32->bf16 conversion: W_stack | spikes | W_embed(used dates) ----------------
__global__ __launch_bounds__(256) void cvt_all(const float* __restrict__ Ws,
                                               const float* __restrict__ spk,
                                               const float* __restrict__ We,
                                               const int* __restrict__ date_idx,
                                               u16* __restrict__ oWs, u16* __restrict__ oSpk,
                                               u16* __restrict__ oWe, int do_bf) {
    __shared__ int dates[BATCH];
    if (threadIdx.x < BATCH) dates[threadIdx.x] = date_idx[threadIdx.x];
    __syncthreads();
    const size_t NW = (size_t)HIDDEN * KSTACK / 4;
    const size_t NS = (size_t)BATCH * TT * CC / 4;
    const size_t NE = (size_t)N_DATES * D_IN * CC / 4;
    const unsigned DSZ = (unsigned)(D_IN * CC / 4);
    const size_t total = do_bf ? (NW + NS + NE) : NW;
    for (size_t i = (size_t)blockIdx.x * 256 + threadIdx.x; i < total; i += (size_t)gridDim.x * 256) {
        const float* src; u16* dst; size_t off;
        if (i < NW)            { src = Ws;  dst = oWs;  off = i; }
        else if (i < NW + NS)  { src = spk; dst = oSpk; off = i - NW; }
        else {
            off = i - NW - NS;
            const int date = (int)((unsigned)off / DSZ);
            bool used = false;
            #pragma unroll
            for (int b = 0; b < BATCH; ++b) used |= (dates[b] == date);
            if (!used) continue;
            src = We; dst = oWe;
        }
        float4 v = *(const float4*)(src + off * 4);
        ushort4 o = make_ushort4(f2bf(v.x), f2bf(v.y), f2bf(v.z), f2bf(v.w));
        *(ushort4*)(dst + off * 4) = o;
    }
}

// ---------------- GEMM1 (bf16): 256Mx192N tile, 4 waves, 2-slot dbuf, 2 blocks/CU ----------------
// (verified round 11 — unchanged)
__global__ __launch_bounds__(256, 2) void gemm1_bf(const u16* __restrict__ spk,
                                                   const u16* __restrict__ wemb,
                                                   const float* __restrict__ b_embed,
                                                   const int* __restrict__ date_idx,
                                                   u16* __restrict__ x1) {
    const int nwg = 512;
    const int cpx = nwg / 8;                  // 64
    const int f   = blockIdx.x;
    const int swz = (f & 7) * cpx + (f >> 3); // bijective (nwg % 8 == 0)
    const int bb  = swz >> 5;
    const int rem = swz & 31;
    const int m0  = (rem >> 4) * 256;
    const int n0  = (rem & 15) * 192;

    const int date = date_idx[bb];
    const u16* A  = spk  + (size_t)bb   * TT * CC;
    const u16* Bw = wemb + (size_t)date * D_IN * CC;
    const int S = CC / 32;                    // 24

    __shared__ u16 Asm[2][128 * 64];
    __shared__ u16 Bsm[2][96 * 64];

    const int tid  = threadIdx.x;
    const int lane = tid & 63;
    const int wave = tid >> 6;
    const int wm = wave >> 1;
    const int wn = wave & 1;

    const int lrow  = lane >> 3;
    const int scol  = ((lane & 7) ^ lrow) << 3;
    const int chalf = scol >> 5;
    const int gk    = scol & 31;

    f32x4 acc[8][6] = {};

    auto STAGE = [&](int slice, int slot) {
        const int k0 = slice * 32;
        u16* Ad = Asm[slot];
        u16* Bd = Bsm[slot];
        #pragma unroll
        for (int i = 0; i < 4; ++i) {
            const int rbase = wave * 32 + i * 8;
            const int tr = 2 * (rbase + lrow) + chalf;
            gload16(A + (size_t)(m0 + tr) * CC + k0 + gk, Ad + rbase * 64);
        }
        #pragma unroll
        for (int i = 0; i < 3; ++i) {
            const int rbase = wave * 24 + i * 8;
            const int tr = 2 * (rbase + lrow) + chalf;
            gload16(Bw + (size_t)(n0 + tr) * CC + k0 + gk, Bd + rbase * 64);
        }
    };

    const int krow  = lane & 15;
    const int kcol  = (lane >> 4) << 3;
    const int cfrag = (kcol + ((krow & 1) << 5)) ^ ((krow >> 1) << 3);
    const int urow  = krow >> 1;

    STAGE(0, 0); STAGE(1, 1);
    for (int t = 0; t < S; ++t) {
        if (t + 1 < S) { asm volatile("s_waitcnt vmcnt(7)" ::: "memory"); }
        else           { asm volatile("s_waitcnt vmcnt(0)" ::: "memory"); }
        __builtin_amdgcn_s_barrier();
        const u16* Ab = Asm[t & 1];
        const u16* Bb = Bsm[t & 1];
        bf16x8 bfr[6];
        #pragma unroll
        for (int j = 0; j < 6; ++j)
            bfr[j] = lds_read8(&Bb[(wn * 48 + j * 8 + urow) * 64 + cfrag]);
        __builtin_amdgcn_s_setprio(1);
        #pragma unroll
        for (int i = 0; i < 8; ++i) {
            bf16x8 af = lds_read8(&Ab[(wm * 64 + i * 8 + urow) * 64 + cfrag]);
            #pragma unroll
            for (int j = 0; j < 6; ++j)
                acc[i][j] = __builtin_amdgcn_mfma_f32_16x16x32_bf16(af, bfr[j], acc[i][j], 0, 0, 0);
        }
        __builtin_amdgcn_s_setprio(0);
        __builtin_amdgcn_s_barrier();
        if (t + 2 < S) STAGE(t + 2, t & 1);
    }

    const float* be = b_embed + (size_t)date * D_IN;
    #pragma unroll
    for (int i = 0; i < 8; ++i) {
        #pragma unroll
        for (int j = 0; j < 6; ++j) {
            const int col  = n0 + wn * 96 + j * 16 + (lane & 15);
            const float bias = be[col];
            const int rbase = m0 + wm * 128 + i * 16 + ((lane >> 4) << 2);
            #pragma unroll
            for (int q = 0; q < 4; ++q) {
                float v = acc[i][j][q] + bias;
                float g = 0.5f * v * (1.0f + erff(v * 0.70710678118654752f)) * 32.0f;
                x1[(size_t)bb * TT * D_IN + (size_t)(rbase + q) * D_IN + col] = f2bf(g);
            }
        }
    }
}

// ---------------- GEMM1 (f32 fallback) ----------------
__global__ __launch_bounds__(256) void gemm1_f32(const float* __restrict__ spikes,
                                                 const float* __restrict__ W_embed,
                                                 const float* __restrict__ b_embed,
                                                 const int* __restrict__ date_idx,
                                                 u16* __restrict__ x1) {
    const int m0 = blockIdx.x * 128;
    const int n0 = blockIdx.y * 128;
    const int bb = blockIdx.z;
    const int date = date_idx[bb];
    const float* A  = spikes  + (size_t)bb  * TT * CC;
    const float* Bw = W_embed + (size_t)date * D_IN * CC;

    __shared__ u16 As[128 * 64];
    __shared__ u16 Bs[128 * 64];

    const int tid  = threadIdx.x;
    const int lane = tid & 63;
    const int wave = tid >> 6;
    const int wm = wave >> 1, wn = wave & 1;

    f32x4 acc[4][4] = {};

    for (int k0 = 0; k0 < CC; k0 += 64) {
        {
            const int c4 = tid & 15;
            int r = tid >> 4;
            #pragma unroll
            for (int p = 0; p < 8; ++p, r += 16) {
                float4 va = *(const float4*)(A  + (size_t)(m0 + r) * CC + k0 + c4 * 4);
                float4 vb = *(const float4*)(Bw + (size_t)(n0 + r) * CC + k0 + c4 * 4);
                const int col = c4 * 4;
                const int idx = r * 64 + (col ^ ((r & 7) << 3));
                *(ushort4*)(&As[idx]) = make_ushort4(f2bf(va.x), f2bf(va.y), f2bf(va.z), f2bf(va.w));
                *(ushort4*)(&Bs[idx]) = make_ushort4(f2bf(vb.x), f2bf(vb.y), f2bf(vb.z), f2bf(vb.w));
            }
        }
        __syncthreads();
        #pragma unroll
        for (int kk = 0; kk < 64; kk += 32) {
            bf16x8 af[4], bfr[4];
            const int krow = lane & 15;
            const int kcol = kk + ((lane >> 4) << 3);
            #pragma unroll
            for (int i = 0; i < 4; ++i) {
                const int ra = wm * 64 + i * 16 + krow;
                af[i]  = lds_read8(&As[ra * 64 + (kcol ^ ((ra & 7) << 3))]);
                const int rb = wn * 64 + i * 16 + krow;
                bfr[i] = lds_read8(&Bs[rb * 64 + (kcol ^ ((rb & 7) << 3))]);
            }
            #pragma unroll
            for (int i = 0; i < 4; ++i)
                #pragma unroll
                for (int j = 0; j < 4; ++j)
                    acc[i][j] = __builtin_amdgcn_mfma_f32_16x16x32_bf16(af[i], bfr[j], acc[i][j], 0, 0, 0);
        }
        __syncthreads();
    }

    const float* be = b_embed + (size_t)date * D_IN;
    #pragma unroll
    for (int i = 0; i < 4; ++i) {
        #pragma unroll
        for (int j = 0; j < 4; ++j) {
            const int col  = n0 + wn * 64 + j * 16 + (lane & 15);
            const float bias = be[col];
            const int rbase = m0 + wm * 64 + i * 16 + ((lane >> 4) << 2);
            #pragma unroll
            for (int q = 0; q < 4; ++q) {
                float v = acc[i][j][q] + bias;
                float g = 0.5f * v * (1.0f + erff(v * 0.70710678118654752f)) * 32.0f;
                x1[(size_t)bb * TT * D_IN + (size_t)(rbase + q) * D_IN + col] = f2bf(g);
            }
        }
    }
}

// ---------------- GEMM2: 256Mx128N tile, 4 waves, 3-slot ring, 2 blocks/CU ----------------
// (verified round 11/13 — 110 us, MfmaUtil 42%, 0 conflicts, FETCH 123 MB. The two
// 32x32-shape attempts regressed: R14 +read-conflicts, R15 -coalescing.)
template <bool WRITE_PART>
__global__ __launch_bounds__(256, 4) void gemm2(const u16* __restrict__ x1,
                                                const u16* __restrict__ Wbf,
                                                float* __restrict__ part,
                                                const float* __restrict__ b_stack,
                                                const float* __restrict__ pos_table,
                                                const int* __restrict__ tstamp,
                                                float* __restrict__ out,
                                                int KS) {
    const int nwg = 8 * KS * BATCH;
    const int cpx = nwg / 8;
    const int f   = blockIdx.x;
    const int swz = (f & 7) * cpx + (f >> 3);   // bijective (nwg % 8 == 0)
    const int bb  = swz / (8 * KS);
    const int rem = swz % (8 * KS);
    const int ks  = rem / 8;
    const int n0  = (rem % 8) * 128;

    const int KCH  = KSTACK / KS;
    const int kbeg = ks * KCH;
    const int S    = KCH / 32;
    const u16* Xb = x1 + (size_t)bb * TT * D_IN;

    __shared__ u16 Asm[3][128 * 64];
    __shared__ u16 Bsm[3][64 * 64];

    const int tid  = threadIdx.x;
    const int lane = tid & 63;
    const int wave = tid >> 6;
    const int wm = wave >> 1;
    const int wn = wave & 1;

    const int lrow  = lane >> 3;
    const int scol  = ((lane & 7) ^ lrow) << 3;
    const int chalf = scol >> 5;
    const int gk    = scol & 31;

    f32x4 acc[8][4] = {};

    auto STAGE = [&](int slice, int slot) {
        const int k0 = kbeg + slice * 32;
        const int s  = k0 / D_IN;            // window slot (32 | 3072, never straddles)
        const int d0 = k0 % D_IN;
        u16* Ad = Asm[slot];
        u16* Bd = Bsm[slot];
        #pragma unroll
        for (int p = 0; p < 4; ++p) {        // A gather: 128 lds rows
            const int rbase = (wave + 4 * p) * 8;
            const int tr = 2 * (rbase + lrow) + chalf;        // tile row 0..255
            gload16(Xb + (size_t)(2 * tr + s) * D_IN + d0 + gk, Ad + rbase * 64);
        }
        #pragma unroll
        for (int p = 0; p < 2; ++p) {        // B: 64 lds rows
            const int rbase = (wave + 4 * p) * 8;
            const int tr = 2 * (rbase + lrow) + chalf;        // tile row 0..127
            gload16(Wbf + (size_t)(n0 + tr) * KSTACK + k0 + gk, Bd + rbase * 64);
        }
    };

    const int krow  = lane & 15;
    const int kcol  = (lane >> 4) << 3;
    const int cfrag = (kcol + ((krow & 1) << 5)) ^ ((krow >> 1) << 3);
    const int urow  = krow >> 1;

    STAGE(0, 0); STAGE(1, 1);
    int cur = 0;
    for (int t = 0; t < S; ++t) {
        if (t + 1 < S) { asm volatile("s_waitcnt vmcnt(6)" ::: "memory"); }
        else           { asm volatile("s_waitcnt vmcnt(0)" ::: "memory"); }
        __builtin_amdgcn_s_barrier();
        const u16* Ab = Asm[cur];
        const u16* Bb = Bsm[cur];
        bf16x8 af[8], bfr[4];
        #pragma unroll
        for (int i = 0; i < 8; ++i)
            af[i] = lds_read8(&Ab[(wm * 64 + i * 8 + urow) * 64 + cfrag]);
        #pragma unroll
        for (int j = 0; j < 4; ++j)
            bfr[j] = lds_read8(&Bb[(wn * 32 + j * 8 + urow) * 64 + cfrag]);
        if (t + 2 < S) {
            const int slot2 = (cur + 2 >= 3) ? cur - 1 : cur + 2;
            STAGE(t + 2, slot2);
        }
        __builtin_amdgcn_s_setprio(1);
        #pragma unroll
        for (int i = 0; i < 8; ++i)
            #pragma unroll
            for (int j = 0; j < 4; ++j)
                acc[i][j] = __builtin_amdgcn_mfma_f32_16x16x32_bf16(af[i], bfr[j], acc[i][j], 0, 0, 0);
        __builtin_amdgcn_s_setprio(0);
        cur = (cur + 1 >= 3) ? 0 : cur + 1;
    }

    if (WRITE_PART) {
        float* pt = part + ((size_t)(ks * BATCH + bb) * 256) * HIDDEN;
        #pragma unroll
        for (int i = 0; i < 8; ++i) {
            #pragma unroll
            for (int j = 0; j < 4; ++j) {
                const int col = n0 + wn * 64 + j * 16 + (lane & 15);
                const int rb  = wm * 128 + i * 16 + ((lane >> 4) << 2);
                #pragma unroll
                for (int q = 0; q < 4; ++q)
                    pt[(size_t)(rb + q) * HIDDEN + col] = acc[i][j][q];
            }
        }
    } else {
        #pragma unroll
        for (int i = 0; i < 8; ++i) {
            #pragma unroll
            for (int j = 0; j < 4; ++j) {
                const int col = n0 + wn * 64 + j * 16 + (lane & 15);
                const int lb  = wm * 128 + i * 16 + ((lane >> 4) << 2);
                #pragma unroll
                for (int q = 0; q < 4; ++q) {
                    const int l = lb + q;
                    if (l < LL) {
                        const int tsv = tstamp[bb * TT + l];
                        float v = acc[i][j][q] + b_stack[col] + pos_table[(size_t)tsv * HIDDEN + col];
                        out[(size_t)bb * OUTROWS * HIDDEN + (size_t)(2 + l) * HIDDEN + col] = v;
                    }
                }
            }
        }
    }
}

// ---------------- reduce partials + bias + pos_table + misc tail (fused) ----------------
// Blocks [0, 4080): reduction of part -> out rows 2.. ; blocks [4080, 4096): rows 0/1 + mask + ts.
#define NRED 4080   // BATCH*LL*(HIDDEN/4)/256
__global__ __launch_bounds__(256) void reduce_ep(const float* __restrict__ part,
                                                 const float* __restrict__ b_stack,
                                                 const float* __restrict__ pos_table,
                                                 const int* __restrict__ tstamp,
                                                 const int* __restrict__ smask,
                                                 const int* __restrict__ mask_idx_p,
                                                 const int* __restrict__ session_idx_p,
                                                 const float* __restrict__ prompt_table,
                                                 const float* __restrict__ session_table,
                                                 float* __restrict__ out,
                                                 int KS) {
    const int tid = threadIdx.x;
    if (blockIdx.x < NRED) {
        const int idx = blockIdx.x * 256 + tid;
        const int c4  = idx & (HIDDEN / 4 - 1);
        const int r   = idx >> 8;
        const int l  = r % LL;
        const int bb = r / LL;
        float4 v = make_float4(0.f, 0.f, 0.f, 0.f);
        for (int ks = 0; ks < KS; ++ks) {
            float4 p = *(const float4*)(part + ((size_t)(ks * BATCH + bb) * 256 + l) * HIDDEN + c4 * 4);
            v.x += p.x; v.y += p.y; v.z += p.z; v.w += p.w;
        }
        const int tsv = tstamp[bb * TT + l];
        float4 bs = *(const float4*)(b_stack + c4 * 4);
        float4 ps = *(const float4*)(pos_table + (size_t)tsv * HIDDEN + c4 * 4);
        v.x += bs.x + ps.x; v.y += bs.y + ps.y; v.z += bs.z + ps.z; v.w += bs.w + ps.w;
        *(float4*)(out + ((size_t)bb * OUTROWS + 2 + l) * HIDDEN + c4 * 4) = v;
    } else {
        const int bb = blockIdx.x - NRED;
        const int mi = mask_idx_p[0];
        const int si = session_idx_p[0];
        float* xb = out + (size_t)bb * OUTROWS * HIDDEN;
        for (int i = tid; i < HIDDEN; i += 256) {
            xb[i]          = session_table[(size_t)si * HIDDEN + i];
            xb[HIDDEN + i] = prompt_table[(size_t)mi * HIDDEN + i];
        }
        float* maskout = out + (size_t)BATCH * OUTROWS * HIDDEN + (size_t)bb * OUTROWS;
        float* tsout   = out + (size_t)BATCH * OUTROWS * HIDDEN + (size_t)BATCH * OUTROWS + (size_t)bb * OUTROWS;
        for (int j = tid; j < OUTROWS; j += 256) {
            if (j == 0)      { maskout[0] = 1.0f; tsout[0] = 0.0f; }
            else if (j == 1) { maskout[1] = 1.0f; tsout[1] = 1.0f; }
            else {
                const int l = j - 2;
                int m = 1;
                #pragma unroll
                for (int s = 0; s < 4; ++s) m *= smask[bb * TT + 2 * l + s];
                maskout[j] = (float)m;
                tsout[j]   = (float)(tstamp[bb * TT + l] + 2);
            }
        }
    }
}

// ---------------- standalone misc tail (fallback path, KS==0) ----------------
__global__ __launch_bounds__(256) void epilogue_misc(const int* __restrict__ smask,
                                                     const int* __restrict__ tstamp,
                                                     const int* __restrict__ mask_idx_p,
                                                     const int* __restrict__ session_idx_p,
                                                     const float* __restrict__ prompt_table,
                                                     const float* __restrict__ session_table,
                                                     float* __restrict__ out) {
    const int bb = blockIdx.x;
    const int tid = threadIdx.x;
    const int mi = mask_idx_p[0];
    const int si = session_idx_p[0];
    float* xb = out + (size_t)bb * OUTROWS * HIDDEN;
    for (int i = tid; i < HIDDEN; i += 256) {
        xb[i]          = session_table[(size_t)si * HIDDEN + i];
        xb[HIDDEN + i] = prompt_table[(size_t)mi * HIDDEN + i];
    }
    float* maskout = out + (size_t)BATCH * OUTROWS * HIDDEN + (size_t)bb * OUTROWS;
    float* tsout   = out + (size_t)BATCH * OUTROWS * HIDDEN + (size_t)BATCH * OUTROWS + (size_t)bb * OUTROWS;
    for (int j = tid; j < OUTROWS; j += 256) {
        if (j == 0)      { maskout[0] = 1.0f; tsout[0] = 0.0f; }
        else if (j == 1) { maskout[1] = 1.0f; tsout[1] = 1.0f; }
        else {
            const int l = j - 2;
            int m = 1;
            #pragma unroll
            for (int s = 0; s < 4; ++s) m *= smask[bb * TT + 2 * l + s];
            maskout[j] = (float)m;
            tsout[j]   = (float)(tstamp[bb * TT + l] + 2);
        }
    }
}

extern "C" void kernel_launch(void* const* d_in, const int* in_sizes, int n_in,
                              void* d_out, int out_size, void* d_ws, size_t ws_size,
                              hipStream_t stream) {
    const float* spikes      = (const float*)d_in[0];
    const int*   spikes_mask = (const int*)d_in[1];
    const int*   tstamp      = (const int*)d_in[2];
    const int*   date_idx    = (const int*)d_in[3];
    const int*   mask_idx    = (const int*)d_in[4];
    const int*   session_idx = (const int*)d_in[5];
    const float* W_embed     = (const float*)d_in[6];
    const float* b_embed     = (const float*)d_in[7];
    const float* W_stack     = (const float*)d_in[8];
    const float* b_stack     = (const float*)d_in[9];
    const float* pos_table   = (const float*)d_in[10];
    const float* prompt_tab  = (const float*)d_in[11];
    const float* session_tab = (const float*)d_in[12];
    float* out = (float*)d_out;

    const size_t X1_B   = (size_t)BATCH * TT * D_IN * 2;
    const size_t WBF_B  = (size_t)HIDDEN * KSTACK * 2;
    const size_t PART_B = (size_t)BATCH * 256 * HIDDEN * 4;
    const size_t SPK_B  = (size_t)BATCH * TT * CC * 2;
    const size_t WEMB_B = (size_t)N_DATES * D_IN * CC * 2;
    const size_t BASE   = X1_B + WBF_B;
    const size_t UNION_BF = SPK_B + WEMB_B;

    u16*   x1    = (u16*)d_ws;
    u16*   Wbf   = (u16*)((char*)d_ws + X1_B);
    u16*   spkbf = (u16*)((char*)d_ws + BASE);
    u16*   wembf = (u16*)((char*)d_ws + BASE + SPK_B);
    float* part  = (float*)((char*)d_ws + BASE);

    const bool use_bf = (ws_size >= BASE + UNION_BF);
    int KS = 0;
    if (use_bf) KS = 4;
    else {
        size_t rem = (ws_size > BASE) ? (ws_size - BASE) : 0;
        KS = (int)(rem / PART_B); if (KS > 4) KS = 4;
    }

    cvt_all<<<2048, 256, 0, stream>>>(W_stack, spikes, W_embed, date_idx,
                                      Wbf, spkbf, wembf, use_bf ? 1 : 0);

    if (use_bf) {
        gemm1_bf<<<512, 256, 0, stream>>>(spkbf, wembf, b_embed, date_idx, x1);
    } else {
        gemm1_f32<<<dim3(TT / 128, D_IN / 128, BATCH), 256, 0, stream>>>(spikes, W_embed, b_embed, date_idx, x1);
    }

    if (KS > 0) {
        gemm2<true><<<8 * KS * BATCH, 256, 0, stream>>>(x1, Wbf, part, b_stack, pos_table, tstamp, out, KS);
        reduce_ep<<<NRED + BATCH, 256, 0, stream>>>(part, b_stack, pos_table, tstamp,
                                                    spikes_mask, mask_idx, session_idx,
                                                    prompt_tab, session_tab, out, KS);
    } else {
        gemm2<false><<<8 * 1 * BATCH, 256, 0, stream>>>(x1, Wbf, part, b_stack, pos_table, tstamp, out, 1);
        epilogue_misc<<<BATCH, 256, 0, stream>>>(spikes_mask, tstamp, mask_idx, session_idx,
                                                 prompt_tab, session_tab, out);
    }
}